// Round 1
// baseline (560.915 us; speedup 1.0000x reference)
//
#include <hip/hip_runtime.h>

#define L2E 1.4426950408889634f
#define LN2 0.6931471805599453f
#define NEG (-1e30f)

constexpr int Bc = 16, Tc = 160, Uc = 80, U1 = 81, Vc = 512, DD = 240;
// ws layout (floats): blankD [16][240][81], labD [16][240][81], loss [16]
// blankD[b][s][u] = blank_lp[b][t][u] with s=t+u ; labD[b][s][u] = lab_lp[b][t][u]

__device__ __forceinline__ float laddexp(float a, float b) {
    float m = fmaxf(a, b);
    float d = fminf(a, b) - m;                       // <= 0
    float e = __builtin_amdgcn_exp2f(d * L2E);       // exp(d)
    return fmaf(LN2, __builtin_amdgcn_logf(1.0f + e), m);  // m + log1p(e)
}

// One wave per (b,t,u) row of 512 logits: logsumexp + write blank/label log-probs
// in anti-diagonal layout.
__global__ __launch_bounds__(256) void k_lse(const float* __restrict__ logits,
                                             const int* __restrict__ targets,
                                             float* __restrict__ blankD,
                                             float* __restrict__ labD) {
    const int lane = threadIdx.x & 63;
    const int wid  = threadIdx.x >> 6;
    const int r    = blockIdx.x * 4 + wid;          // row index, grid*4 == B*T*U1 exactly
    const int u    = r % U1;
    const int bt   = r / U1;
    const int t    = bt % Tc;
    const int b    = bt / Tc;

    const float* __restrict__ row = logits + (size_t)r * Vc;
    const float4 x0 = reinterpret_cast<const float4*>(row)[lane];        // floats [4l, 4l+3]
    const float4 x1 = reinterpret_cast<const float4*>(row)[lane + 64];   // floats [256+4l, ...]

    float m = fmaxf(fmaxf(fmaxf(x0.x, x0.y), fmaxf(x0.z, x0.w)),
                    fmaxf(fmaxf(x1.x, x1.y), fmaxf(x1.z, x1.w)));
#pragma unroll
    for (int o = 32; o; o >>= 1) m = fmaxf(m, __shfl_xor(m, o));

    float s = __builtin_amdgcn_exp2f((x0.x - m) * L2E)
            + __builtin_amdgcn_exp2f((x0.y - m) * L2E)
            + __builtin_amdgcn_exp2f((x0.z - m) * L2E)
            + __builtin_amdgcn_exp2f((x0.w - m) * L2E)
            + __builtin_amdgcn_exp2f((x1.x - m) * L2E)
            + __builtin_amdgcn_exp2f((x1.y - m) * L2E)
            + __builtin_amdgcn_exp2f((x1.z - m) * L2E)
            + __builtin_amdgcn_exp2f((x1.w - m) * L2E);
#pragma unroll
    for (int o = 32; o; o >>= 1) s += __shfl_xor(s, o);

    if (lane == 0) {
        const float lse = fmaf(LN2, __builtin_amdgcn_logf(s), m);
        const int sidx = t + u;
        const size_t idx = ((size_t)b * DD + sidx) * U1 + u;
        blankD[idx] = row[Vc - 1] - lse;            // L1 hit: wave just read this line
        if (u < Uc) {
            labD[idx] = row[targets[b * Uc + u]] - lse;
        }
    }
}

// One wave per batch: anti-diagonal wavefront DP fully in registers.
// lane l owns u0=2l and u1=2l+1; alpha[t][u-1] comes via one __shfl_up.
__global__ __launch_bounds__(64) void k_dp(const float* __restrict__ blankD,
                                           const float* __restrict__ labD,
                                           const int* __restrict__ llen,
                                           const int* __restrict__ tlen,
                                           float* __restrict__ loss) {
    const int b    = blockIdx.x;
    const int lane = threadIdx.x;
    const int u0 = 2 * lane, u1 = u0 + 1;
    const bool v0 = (u0 <= Uc), v1 = (u1 <= Uc);
    const int cu0  = v0 ? u0 : Uc;                  // clamped (in-bounds) addresses
    const int cu1  = v1 ? u1 : Uc;
    const int cu0m = (cu0 >= 1) ? (cu0 - 1) : 0;

    const float* __restrict__ bl = blankD + (size_t)b * DD * U1;
    const float* __restrict__ la = labD  + (size_t)b * DD * U1;
    const int tl = llen[b], ul = tlen[b];
    const int d_end = tl - 1 + ul;                  // in [119, 239]

    float a0 = (u0 == 0) ? 0.0f : NEG;              // alpha on diagonal d=0
    float a1 = NEG;
    float res = NEG;

    // register prefetch buffers, depth 8 (one diagonal group)
    float pb0[8], pb1[8], pl0[8], pl1[8];
#pragma unroll
    for (int k = 0; k < 8; ++k) {                   // data s=0..7 for d=1..8
        pb0[k] = bl[k * U1 + cu0];
        pb1[k] = bl[k * U1 + cu1];
        pl0[k] = la[k * U1 + cu0m];
        pl1[k] = la[k * U1 + cu0];
    }

    for (int g = 0; g < 30; ++g) {
        const int dbase = 1 + g * 8;
        float nb0[8], nb1[8], nl0[8], nl1[8];
#pragma unroll
        for (int k = 0; k < 8; ++k) {               // prefetch next group's diagonals
            int s = dbase + 7 + k;
            if (s > DD - 1) s = DD - 1;             // clamp: values unused, address safe
            nb0[k] = bl[s * U1 + cu0];
            nb1[k] = bl[s * U1 + cu1];
            nl0[k] = la[s * U1 + cu0m];
            nl1[k] = la[s * U1 + cu0];
        }
#pragma unroll
        for (int k = 0; k < 8; ++k) {
            const int d = dbase + k;
            const float a1m = __shfl_up(a1, 1);     // old alpha at u0-1 (diag d-1)
            const int t0 = d - u0, t1 = d - u1;
            float top0 = (t0 >= 1) ? (a0 + pb0[k]) : NEG;
            float lef0 = (u0 >= 1) ? (a1m + pl0[k]) : NEG;
            float top1 = (t1 >= 1) ? (a1 + pb1[k]) : NEG;
            float lef1 = a0 + pl1[k];               // u1 >= 1 always
            float na0 = laddexp(top0, lef0);
            float na1 = laddexp(top1, lef1);
            na0 = (v0 && t0 >= 0 && t0 < Tc) ? na0 : NEG;
            na1 = (v1 && t1 >= 0 && t1 < Tc) ? na1 : NEG;
            a0 = na0; a1 = na1;
            if (d == d_end) {                       // endpoint: alpha + blank_lp[tl-1][ul]
                if (u0 == ul) res = a0 + bl[d * U1 + u0];
                if (u1 == ul) res = a1 + bl[d * U1 + u1];
            }
        }
#pragma unroll
        for (int k = 0; k < 8; ++k) {
            pb0[k] = nb0[k]; pb1[k] = nb1[k]; pl0[k] = nl0[k]; pl1[k] = nl1[k];
        }
    }
    if (u0 == ul || u1 == ul) loss[b] = -res;
}

__global__ __launch_bounds__(64) void k_final(const float* __restrict__ loss,
                                              float* __restrict__ out) {
    float s = (threadIdx.x < Bc) ? loss[threadIdx.x] : 0.0f;
#pragma unroll
    for (int o = 32; o; o >>= 1) s += __shfl_xor(s, o);
    if (threadIdx.x == 0) out[0] = s * (1.0f / Bc);
}

extern "C" void kernel_launch(void* const* d_in, const int* in_sizes, int n_in,
                              void* d_out, int out_size, void* d_ws, size_t ws_size,
                              hipStream_t stream) {
    const float* logits  = (const float*)d_in[0];
    const int*   targets = (const int*)d_in[1];
    const int*   llen    = (const int*)d_in[2];
    const int*   tlen    = (const int*)d_in[3];

    float* ws     = (float*)d_ws;
    float* blankD = ws;
    float* labD   = ws + (size_t)Bc * DD * U1;          // +311040
    float* loss   = labD + (size_t)Bc * DD * U1;        // +311040
    float* out    = (float*)d_out;

    const int nrows = Bc * Tc * U1;                     // 207360, divisible by 4
    k_lse<<<dim3(nrows / 4), dim3(256), 0, stream>>>(logits, targets, blankD, labD);
    k_dp<<<dim3(Bc), dim3(64), 0, stream>>>(blankD, labD, llen, tlen, loss);
    k_final<<<dim3(1), dim3(64), 0, stream>>>(loss, out);
}